// Round 16
// baseline (383.469 us; speedup 1.0000x reference)
//
#include <hip/hip_runtime.h>

// Mamba block forward. Round 16: combine folded into pass-B prologue
// (batched aggregate loads + short serial fold), 9 launches. R15 base.
constexpr int B  = 2, L = 1024, DM = 512, DI = 1024, NST = 16, PW = 97;
constexpr int ML = B * L;                   // 2048 rows
constexpr int NCHUNK = 32, CL = L / NCHUNK; // 32 chunks x 32 steps
constexpr int NLANES = B * DI * NST;        // 32768 scan lanes

#define DEV_INLINE __device__ __forceinline__

typedef __attribute__((ext_vector_type(8))) short bf16x8;   // 8 bf16 (4 VGPRs)
typedef __attribute__((ext_vector_type(4))) float f32x4;    // 4 fp32 acc
typedef __attribute__((ext_vector_type(2))) float v2f;      // packed f32 pair

DEV_INLINE float sigmoidf_(float x) { return 1.f / (1.f + __expf(-x)); }
DEV_INLINE unsigned short f2bf(float f) {
  unsigned int u = __float_as_uint(f);
  return (unsigned short)((u + 0x7FFFu + ((u >> 16) & 1u)) >> 16);  // RNE
}
DEV_INLINE float bf2f(unsigned short u) {
  return __uint_as_float((unsigned)u << 16);
}

// packed helpers (target v_pk_fma_f32 / v_pk_mul_f32)
DEV_INLINE v2f pk_fma(float s, v2f v, v2f c) {
  v2f r; r.x = fmaf(s, v.x, c.x); r.y = fmaf(s, v.y, c.y); return r;
}
DEV_INLINE v2f pk_mul(float s, v2f v) {
  v2f r; r.x = s * v.x; r.y = s * v.y; return r;
}
DEV_INLINE v2f swapneg(v2f w) {   // (wr,wi) -> (-wi, wr)  [i * w]
  v2f r; r.x = -w.y; r.y = w.x; return r;
}

#if __has_builtin(__builtin_amdgcn_exp2f)
#define EXP2F(x) __builtin_amdgcn_exp2f(x)
#else
#define EXP2F(x) exp2f(x)
#endif
#if __has_builtin(__builtin_amdgcn_sinf)
#define SINR(x) __builtin_amdgcn_sinf(x)   // sin(2*pi*x), x in revolutions
#define COSR(x) __builtin_amdgcn_cosf(x)
#else
#define SINR(x) __sinf((x) * 6.2831853f)
#define COSR(x) __cosf((x) * 6.2831853f)
#endif

#if __has_builtin(__builtin_amdgcn_global_load_lds)
#define HAVE_GLDS 1
#define GLOAD16(g, l)                                                         \
  __builtin_amdgcn_global_load_lds(                                           \
      (const __attribute__((address_space(1))) unsigned int*)(g),             \
      (__attribute__((address_space(3))) unsigned int*)(l), 16, 0, 0)
#else
#define HAVE_GLDS 0
#endif

// Taylor sin/cos order 7/6 (radians), |th| <= ~1, err < 3e-5. Shares t2.
DEV_INLINE void sincos_poly(float th, float& s, float& c) {
  float t2 = th * th;
  float u = fmaf(t2, -1.9841270e-4f, 8.3333333e-3f);
  u = fmaf(t2, u, -0.16666667f);
  u = fmaf(t2, u, 1.f);
  s = th * u;
  float v = fmaf(t2, -1.3888889e-3f, 4.1666667e-2f);
  v = fmaf(t2, v, -0.5f);
  c = fmaf(t2, v, 1.f);
}

// DPP 16-lane add-reduce (quad_perm xor1, xor2, row_ror:4, row_ror:8)
template <int CTRL>
DEV_INLINE float dpp_add(float v) {
  int x = __builtin_amdgcn_update_dpp(0, __float_as_int(v), CTRL, 0xF, 0xF, true);
  return v + __int_as_float(x);
}

// ---------------------------------------------------------------------------
// f32 -> bf16 convert, 3 segments + padded x_proj_w (97->128 rows) as seg 4.
// ---------------------------------------------------------------------------
__global__ __launch_bounds__(256) void cvt4_k(
    const float* __restrict__ i0, unsigned short* __restrict__ o0, int n0,
    const float* __restrict__ i1, unsigned short* __restrict__ o1, int n1,
    const float* __restrict__ i2, unsigned short* __restrict__ o2, int n2,
    const float* __restrict__ xw, unsigned short* __restrict__ xwpb) {
  int i = blockIdx.x * 256 + threadIdx.x;   // in float4 units
  if (i < n0) {
    float4 v = ((const float4*)i0)[i];
    ((ushort4*)o0)[i] = make_ushort4(f2bf(v.x), f2bf(v.y), f2bf(v.z), f2bf(v.w));
  } else if (i < n0 + n1) {
    int off = i - n0;
    float4 v = ((const float4*)i1)[off];
    ((ushort4*)o1)[off] = make_ushort4(f2bf(v.x), f2bf(v.y), f2bf(v.z), f2bf(v.w));
  } else if (i < n0 + n1 + n2) {
    int off = i - n0 - n1;
    float4 v = ((const float4*)i2)[off];
    ((ushort4*)o2)[off] = make_ushort4(f2bf(v.x), f2bf(v.y), f2bf(v.z), f2bf(v.w));
  } else {
    int off = i - n0 - n1 - n2;
    if (off < 128 * 256) {
      int row = off >> 8;
      float4 v = (row < PW) ? ((const float4*)xw)[off] : make_float4(0, 0, 0, 0);
      ((ushort4*)xwpb)[off] = make_ushort4(f2bf(v.x), f2bf(v.y), f2bf(v.z), f2bf(v.w));
    }
  }
}

// ---------------------------------------------------------------------------
// Shared GEMM helpers: global_load_lds staging with SOURCE-side XOR swizzle
// (linear LDS dest); reads use swz().
// ---------------------------------------------------------------------------
DEV_INLINE int swz(int row, int kb) { return (row << 7) + (kb ^ ((row & 7) << 4)); }

DEV_INLINE void stage16(const short* g, char* l) {
#if HAVE_GLDS
  GLOAD16(g, l);
#else
  *(bf16x8*)l = *(const bf16x8*)g;
#endif
}

#define GEMM_STAGE(Abase, Wbase)                                              \
  _Pragma("unroll")                                                           \
  for (int i = 0; i < 2; ++i) {                                               \
    int off = i * 4096 + tid * 16;                                            \
    int row = off >> 7, kb = off & 127;                                       \
    int kel = (kb ^ ((row & 7) << 4)) >> 1;                                   \
    stage16(Abase + (size_t)(bm + row) * K + k0 + kel, ldsb + off);           \
    stage16(Wbase + (size_t)(bn + row) * K + k0 + kel, ldsb + 8192 + off);    \
  }

#define GEMM_MFMA_BODY                                                        \
  _Pragma("unroll")                                                           \
  for (int ks = 0; ks < 2; ++ks) {                                            \
    const int kb = ks * 64 + ((lane >> 4) << 4);                              \
    bf16x8 af = *(const bf16x8*)(ldsb + swz(wv * 16 + (lane & 15), kb));      \
    _Pragma("unroll")                                                         \
    for (int nb = 0; nb < 4; ++nb) {                                          \
      bf16x8 bfv = *(const bf16x8*)(ldsb + 8192 + swz(nb * 16 + (lane & 15), kb)); \
      acc[nb] = __builtin_amdgcn_mfma_f32_16x16x32_bf16(af, bfv, acc[nb], 0, 0, 0); \
    }                                                                         \
  }

// ---------------------------------------------------------------------------
// gemm1: C = xb @ wb1^T (N=2048). z-half tiles (bn >= DI) write silu(v)
// directly to sz; x-half writes xz.
// ---------------------------------------------------------------------------
__global__ __launch_bounds__(256) void gemm1_k(
    const short* __restrict__ A, const short* __restrict__ W,
    float* __restrict__ C, float* __restrict__ szp, int M, int N, int K) {
  __shared__ char ldsb[16384];
  const int tid = threadIdx.x;
  const int lane = tid & 63, wv = tid >> 6;
  const int bm = blockIdx.y * 64, bn = blockIdx.x * 64;

  f32x4 acc[4];
#pragma unroll
  for (int nb = 0; nb < 4; ++nb) acc[nb] = (f32x4){0.f, 0.f, 0.f, 0.f};

  for (int k0 = 0; k0 < K; k0 += 64) {
    GEMM_STAGE(A, W)
    __syncthreads();
    GEMM_MFMA_BODY
    __syncthreads();
  }
  const bool zside = (bn >= DI);
#pragma unroll
  for (int nb = 0; nb < 4; ++nb) {
    int col = bn + nb * 16 + (lane & 15);
    int row0 = bm + wv * 16 + ((lane >> 4) << 2);
#pragma unroll
    for (int j = 0; j < 4; ++j) {
      float v = acc[nb][j];
      if (zside)
        szp[(size_t)(row0 + j) * DI + col - DI] = v * sigmoidf_(v);
      else
        C[(size_t)(row0 + j) * N + col] = v;
    }
  }
}

// 64x64-tile split-K GEMM (proj + gemm2): KS-wide K slice per blockIdx.z.
__global__ __launch_bounds__(256) void gemm_bf16_sk(
    const short* __restrict__ A, const short* __restrict__ W,
    float* __restrict__ P, int M, int N, int K, int KS) {
  __shared__ char ldsb[16384];
  const int tid = threadIdx.x;
  const int lane = tid & 63, wv = tid >> 6;
  const int bm = blockIdx.y * 64, bn = blockIdx.x * 64;
  const int kz = blockIdx.z * KS;
  float* Cp = P + (size_t)blockIdx.z * M * N;

  f32x4 acc[4];
#pragma unroll
  for (int nb = 0; nb < 4; ++nb) acc[nb] = (f32x4){0.f, 0.f, 0.f, 0.f};

  for (int k0 = kz; k0 < kz + KS; k0 += 64) {
    GEMM_STAGE(A, W)
    __syncthreads();
    GEMM_MFMA_BODY
    __syncthreads();
  }
#pragma unroll
  for (int nb = 0; nb < 4; ++nb) {
    int col = bn + nb * 16 + (lane & 15);
    int row0 = bm + wv * 16 + ((lane >> 4) << 2);
#pragma unroll
    for (int j = 0; j < 4; ++j)
      Cp[(size_t)(row0 + j) * N + col] = acc[nb][j];
  }
}

// out = sum of 4 K-slice partials (float4 vectorized)
__global__ __launch_bounds__(256) void addp4_k(
    const float4* __restrict__ p, float4* __restrict__ out) {
  constexpr int NN = ML * DM / 4;
  int i = blockIdx.x * 256 + threadIdx.x;
  float4 a = p[i], b = p[i + NN], c = p[i + 2 * NN], d = p[i + 3 * NN];
  out[i] = make_float4(a.x + b.x + c.x + d.x, a.y + b.y + c.y + d.y,
                       a.z + b.z + c.z + d.z, a.w + b.w + c.w + d.w);
}

// ---------------------------------------------------------------------------
// causal depthwise conv (K=3) + bias + SiLU -> xcb (bf16). Reads x-half only.
// ---------------------------------------------------------------------------
__global__ __launch_bounds__(256) void conv_silu_k(
    const float* __restrict__ xz, const float* __restrict__ cw,
    const float* __restrict__ cb, unsigned short* __restrict__ xcb) {
  int idx = blockIdx.x * 256 + threadIdx.x;   // float4 unit: (m, d4)
  int m = idx >> 8, d4 = (idx & 255) * 4;
  int t = m & (L - 1);
  const float* base = xz + (size_t)m * (2 * DI);
  float4 r2 = *(const float4*)(base + d4);
  float4 r1 = (t >= 1) ? *(const float4*)(base - 2 * DI + d4) : make_float4(0, 0, 0, 0);
  float4 r0 = (t >= 2) ? *(const float4*)(base - 4 * DI + d4) : make_float4(0, 0, 0, 0);
  float wv[12];
  *(float4*)(wv + 0) = *(const float4*)(cw + d4 * 3 + 0);
  *(float4*)(wv + 4) = *(const float4*)(cw + d4 * 3 + 4);
  *(float4*)(wv + 8) = *(const float4*)(cw + d4 * 3 + 8);
  float4 bv = *(const float4*)(cb + d4);
  float rin0[4] = {r0.x, r0.y, r0.z, r0.w};
  float rin1[4] = {r1.x, r1.y, r1.z, r1.w};
  float rin2[4] = {r2.x, r2.y, r2.z, r2.w};
  float bb[4] = {bv.x, bv.y, bv.z, bv.w};
  float xo[4];
#pragma unroll
  for (int j = 0; j < 4; ++j) {
    float v = bb[j];
    v = fmaf(rin0[j], wv[3 * j + 0], v);
    v = fmaf(rin1[j], wv[3 * j + 1], v);
    v = fmaf(rin2[j], wv[3 * j + 2], v);
    xo[j] = v * sigmoidf_(v);
  }
  ((ushort4*)xcb)[idx] = make_ushort4(f2bf(xo[0]), f2bf(xo[1]), f2bf(xo[2]), f2bf(xo[3]));
}

// ---------------------------------------------------------------------------
// FUSED: reduce 8 proj partials -> scatter B/C (interleaved bcc4) + lam,
// keep dt columns in LDS, compute delta = softplus(dt@dt_w^T+dt_b) -> dx2.
// ---------------------------------------------------------------------------
__global__ __launch_bounds__(256) void reduce_delta_k(
    const float* __restrict__ P, const float* __restrict__ dtw,
    const float* __restrict__ dtb, const unsigned short* __restrict__ xcb,
    float* __restrict__ bcc4, float* __restrict__ lamv,
    float2* __restrict__ dx2) {
  __shared__ float pp[2][32];
  const int tid = threadIdx.x;
  const int i = blockIdx.x * 256 + tid;
  const int m = i >> 7, c = i & 127;
  float s = 0.f;
#pragma unroll
  for (int z = 0; z < 8; ++z) s += P[(size_t)z * ML * 128 + i];
  if (c < 32)       pp[tid >> 7][c] = s;
  else if (c < 48)  bcc4[(m * 16 + c - 32) * 4 + 0] = s;
  else if (c < 64)  bcc4[(m * 16 + c - 48) * 4 + 1] = s;
  else if (c < 80)  bcc4[(m * 16 + c - 64) * 4 + 2] = s;
  else if (c < 96)  bcc4[(m * 16 + c - 80) * 4 + 3] = s;
  else if (c == 96) lamv[m] = sigmoidf_(s);
  __syncthreads();
  const int d0 = tid * 4;
  const int m0 = blockIdx.x * 2;
  float4 bb4 = *(const float4*)(dtb + d0);
  float acc[2][4];
#pragma unroll
  for (int r = 0; r < 2; ++r) {
    acc[r][0] = bb4.x; acc[r][1] = bb4.y; acc[r][2] = bb4.z; acc[r][3] = bb4.w;
  }
#pragma unroll
  for (int j = 0; j < 4; ++j) {
    const float4* wrow = (const float4*)(dtw + (size_t)(d0 + j) * 32);
#pragma unroll
    for (int kq = 0; kq < 8; ++kq) {
      float4 w4 = wrow[kq];
#pragma unroll
      for (int r = 0; r < 2; ++r) {
        acc[r][j] = fmaf(pp[r][kq * 4 + 0], w4.x, acc[r][j]);
        acc[r][j] = fmaf(pp[r][kq * 4 + 1], w4.y, acc[r][j]);
        acc[r][j] = fmaf(pp[r][kq * 4 + 2], w4.z, acc[r][j]);
        acc[r][j] = fmaf(pp[r][kq * 4 + 3], w4.w, acc[r][j]);
      }
    }
  }
#pragma unroll
  for (int r = 0; r < 2; ++r) {
    ushort4 xv = ((const ushort4*)xcb)[((size_t)(m0 + r) * DI + d0) >> 2];
    float dl[4];
#pragma unroll
    for (int j = 0; j < 4; ++j) {
      float xq = acc[r][j];
      dl[j] = (xq > 20.f) ? xq : log1pf(__expf(xq));
    }
    *(float4*)(dx2 + (size_t)(m0 + r) * DI + d0) =
        make_float4(dl[0], bf2f(xv.x), dl[1], bf2f(xv.y));
    *(float4*)(dx2 + (size_t)(m0 + r) * DI + d0 + 2) =
        make_float4(dl[2], bf2f(xv.z), dl[3], bf2f(xv.w));
  }
}

// ---------------------------------------------------------------------------
// LDS-staged chunked scan, packed-f32 complex math.
// PASS_B folds the chunk-entry prefix itself (batched loads + short chain).
// ---------------------------------------------------------------------------
template <bool PASS_B>
__global__ __launch_bounds__(256, 8) void scan_pass(
    const float2* __restrict__ dx2, const float* __restrict__ lamv,
    const float4* __restrict__ bcc4, const float* __restrict__ sz,
    const float* __restrict__ A_log, const float* __restrict__ A_imag,
    const float* __restrict__ D_skip,
    float2* __restrict__ aggA, float2* __restrict__ aggU,
    unsigned short* __restrict__ ybuf) {
  __shared__ float4 qx[CL][17];                  // {dlt, xt, bsc, g} (padded)
  __shared__ float2 bcl[PASS_B ? 1 : CL][17];    // pass A: {Br, Bi}
  __shared__ float4 bccl[PASS_B ? CL : 1][17];   // pass B: {Br,Bi,Cr,Ci}
  __shared__ float  ylds[PASS_B ? CL : 1][17];   // y per (t, ch)

  const int tid = threadIdx.x;
  const int n = tid & 15, ch = tid >> 4;
  const int bx = blockIdx.x, c = blockIdx.y;
  const int b = bx >> 6, d0 = (bx & 63) * 16;
  const int d = d0 + ch;
  const int lane = bx * 256 + tid;
  const int t0 = c * CL, mb = b * L;

  // ---- stage chunk into LDS ----
  {
    int t = tid >> 3, pr = tid & 7;              // 32 t x 8 pairs
    size_t row = (size_t)(mb + t0 + t);
    float4 v = *(const float4*)(dx2 + row * DI + d0 + pr * 2);
    float lamt = lamv[row];
    float g0 = lamt * v.x, g1 = lamt * v.z;
    qx[t][pr * 2 + 0] = make_float4(v.x, v.y, v.x - g0, g0);
    qx[t][pr * 2 + 1] = make_float4(v.z, v.w, v.z - g1, g1);
    float4 b0 = bcc4[row * 16 + pr * 2 + 0];
    float4 b1 = bcc4[row * 16 + pr * 2 + 1];
    if constexpr (PASS_B) {
      bccl[t][pr * 2 + 0] = b0;
      bccl[t][pr * 2 + 1] = b1;
    } else {
      bcl[t][pr * 2 + 0] = make_float2(b0.x, b0.y);
      bcl[t][pr * 2 + 1] = make_float2(b1.x, b1.y);
    }
  }

  const float Ar = -__expf(A_log[d * 16 + n]);
  const float Arl = Ar * 1.44269504f;                  // * log2(e)
  const float Ai = A_imag[d * 16 + n];

  v2f Bxp = (v2f){0.f, 0.f};
  if (c > 0) {
    float xp = dx2[(size_t)(mb + t0 - 1) * DI + d].y;
    float4 bp = bcc4[(size_t)(mb + t0 - 1) * 16 + n];
    Bxp.x = bp.x * xp; Bxp.y = bp.y * xp;
  }
  v2f h = (v2f){0.f, 0.f};
  float S = 0.f, Dsk = 0.f;
  if (PASS_B) {
    // fold chunk-entry prefix from raw aggregates (chunks 0..c-1).
    // batched loads (independent) then a <=31-step dependent chain.
    if (c > 0) {
      float2 av[NCHUNK - 1], uv[NCHUNK - 1];
#pragma unroll
      for (int cc = 0; cc < NCHUNK - 1; ++cc) {
        if (cc < c) {
          av[cc] = aggA[cc * NLANES + lane];
          uv[cc] = aggU[cc * NLANES + lane];
        }
      }
#pragma unroll
      for (int cc = 0; cc < NCHUNK - 1; ++cc) {
        if (cc < c) {
          v2f u; u.x = uv[cc].x; u.y = uv[cc].y;
          h = pk_fma(av[cc].x, h, pk_fma(av[cc].y, swapneg(h), u));
        }
      }
    }
    Dsk = D_skip[d];
  }

  __syncthreads();

  // ---- recurrence: pure LDS + packed VALU ----
#pragma unroll
  for (int t = 0; t < CL; ++t) {
    float4 q = qx[t][ch];
    v2f Bv; float Cr_ = 0.f, Ci_ = 0.f;
    if constexpr (PASS_B) {
      float4 p = bccl[t][n];
      Bv.x = p.x; Bv.y = p.y; Cr_ = p.z; Ci_ = p.w;
    } else {
      float2 p = bcl[t][n];
      Bv.x = p.x; Bv.y = p.y;
    }
    float ear = EXP2F(q.x * Arl);
    float sn, cs; sincos_poly(q.x * Ai, sn, cs);
    float ar = ear * cs, ai = ear * sn;
    v2f Bx = pk_mul(q.y, Bv);
    v2f w = pk_fma(q.z, Bxp, h);
    v2f tg = pk_mul(q.w, Bx);
    h = pk_fma(ar, w, pk_fma(ai, swapneg(w), tg));
    Bxp = Bx;
    if constexpr (!PASS_B) {
      S += q.x;
    } else {
      float yc = fmaf(h.y, Ci_, h.x * Cr_);   // Re(h * conj(C))
      yc = dpp_add<0xB1>(yc);
      yc = dpp_add<0x4E>(yc);
      yc = dpp_add<0x124>(yc);
      yc = dpp_add<0x128>(yc);
      if (n == 0) ylds[t][ch] = fmaf(Dsk, q.y, yc);
    }
  }

  if constexpr (!PASS_B) {
    float earS = EXP2F(S * Arl);
    float rvS = S * Ai * 0.15915494f;     // revolutions for HW sin/cos
    float AaR = earS * COSR(rvS);
    float AaI = earS * SINR(rvS);
    int idx = c * NLANES + lane;
    aggA[idx] = make_float2(AaR, AaI);
    aggU[idx] = make_float2(h.x, h.y);
  } else {
    __syncthreads();
    // coalesced epilogue: y * silu(z) -> packed bf16 pairs
    int t = tid >> 3, pr = tid & 7;
    size_t row = (size_t)(mb + t0 + t);
    float2 szv = *(const float2*)(sz + row * DI + d0 + pr * 2);
    float y0 = ylds[t][pr * 2 + 0] * szv.x;
    float y1 = ylds[t][pr * 2 + 1] * szv.y;
    unsigned pk = (unsigned)f2bf(y0) | ((unsigned)f2bf(y1) << 16);
    *(unsigned*)(ybuf + row * DI + d0 + pr * 2) = pk;
  }
}

extern "C" void kernel_launch(void* const* d_in, const int* in_sizes, int n_in,
                              void* d_out, int out_size, void* d_ws, size_t ws_size,
                              hipStream_t stream) {
  const float* x        = (const float*)d_in[0];
  const float* in_proj  = (const float*)d_in[1];
  const float* conv_w   = (const float*)d_in[2];
  const float* conv_b   = (const float*)d_in[3];
  const float* x_proj_w = (const float*)d_in[4];
  const float* dt_w     = (const float*)d_in[5];
  const float* dt_b     = (const float*)d_in[6];
  const float* A_log    = (const float*)d_in[7];
  const float* A_imag   = (const float*)d_in[8];
  const float* D_skip   = (const float*)d_in[9];
  const float* out_proj = (const float*)d_in[10];
  float* out = (float*)d_out;

  float* ws = (float*)d_ws;
  float*  xz    = ws; ws += (size_t)ML * 2 * DI;   // gemm1 out; later partials
  float*  sz    = ws; ws += (size_t)ML * DI;
  float2* dx2   = (float2*)ws; ws += (size_t)ML * DI * 2;
  float*  bcc4  = ws; ws += (size_t)ML * 64;       // float4[ML*16]
  float*  lamv  = ws; ws += ML;
  float2* aggA  = (float2*)ws; ws += (size_t)NCHUNK * NLANES * 2;
  float2* aggU  = (float2*)ws; ws += (size_t)NCHUNK * NLANES * 2;
  unsigned short* xb   = (unsigned short*)ws; ws += (size_t)ML * DM / 2;
  unsigned short* wb1  = (unsigned short*)ws; ws += (size_t)(2 * DI) * DM / 2;
  unsigned short* wb2  = (unsigned short*)ws; ws += (size_t)DM * DI / 2;
  unsigned short* xcb  = (unsigned short*)ws; ws += (size_t)ML * DI / 2;
  unsigned short* xwpb = (unsigned short*)ws; ws += (size_t)128 * DI / 2;
  unsigned short* ybuf = (unsigned short*)ws; ws += (size_t)ML * DI / 2;

  const int n0 = ML * DM / 4, n1 = 2 * DI * DM / 4, n2 = DM * DI / 4;
  const int n3 = 128 * DI / 4;
  cvt4_k<<<(n0 + n1 + n2 + n3 + 255) / 256, 256, 0, stream>>>(
      x, xb, n0, in_proj, wb1, n1, out_proj, wb2, n2, x_proj_w, xwpb);
  gemm1_k<<<dim3(2 * DI / 64, ML / 64), 256, 0, stream>>>(
      (const short*)xb, (const short*)wb1, xz, sz, ML, 2 * DI, DM);
  conv_silu_k<<<ML * DI / 4 / 256, 256, 0, stream>>>(xz, conv_w, conv_b, xcb);
  gemm_bf16_sk<<<dim3(2, ML / 64, 8), 256, 0, stream>>>(
      (const short*)xcb, (const short*)xwpb, xz, ML, 128, DI, 128);
  reduce_delta_k<<<ML * 128 / 256, 256, 0, stream>>>(xz, dt_w, dt_b, xcb,
                                                     bcc4, lamv, dx2);
  scan_pass<false><<<dim3(128, NCHUNK - 1), 256, 0, stream>>>(
      dx2, lamv, (const float4*)bcc4, sz, A_log, A_imag, D_skip,
      aggA, aggU, nullptr);
  scan_pass<true><<<dim3(128, NCHUNK), 256, 0, stream>>>(
      dx2, lamv, (const float4*)bcc4, sz, A_log, A_imag, D_skip,
      aggA, aggU, ybuf);
  gemm_bf16_sk<<<dim3(DM / 64, ML / 64, 4), 256, 0, stream>>>(
      (const short*)ybuf, (const short*)wb2, xz, ML, DM, DI, 256);
  addp4_k<<<ML * DM / 4 / 256, 256, 0, stream>>>((const float4*)xz, (float4*)out);
}

// Round 17
// 126.263 us; speedup vs baseline: 3.0371x; 3.0371x over previous
//
#include <hip/hip_runtime.h>

// Mamba block forward. Round 17: exact revert to Round 15 best (126.8 us).
// Packed-f32 scan, separate combine kernel, silu(z) fused in gemm1.
constexpr int B  = 2, L = 1024, DM = 512, DI = 1024, NST = 16, PW = 97;
constexpr int ML = B * L;                   // 2048 rows
constexpr int NCHUNK = 32, CL = L / NCHUNK; // 32 chunks x 32 steps
constexpr int NLANES = B * DI * NST;        // 32768 scan lanes

#define DEV_INLINE __device__ __forceinline__

typedef __attribute__((ext_vector_type(8))) short bf16x8;   // 8 bf16 (4 VGPRs)
typedef __attribute__((ext_vector_type(4))) float f32x4;    // 4 fp32 acc
typedef __attribute__((ext_vector_type(2))) float v2f;      // packed f32 pair

DEV_INLINE float sigmoidf_(float x) { return 1.f / (1.f + __expf(-x)); }
DEV_INLINE unsigned short f2bf(float f) {
  unsigned int u = __float_as_uint(f);
  return (unsigned short)((u + 0x7FFFu + ((u >> 16) & 1u)) >> 16);  // RNE
}
DEV_INLINE float bf2f(unsigned short u) {
  return __uint_as_float((unsigned)u << 16);
}

// packed helpers: scalar x vector fma / mul (targets v_pk_fma_f32 / v_pk_mul_f32)
DEV_INLINE v2f pk_fma(float s, v2f v, v2f c) {
  v2f r; r.x = fmaf(s, v.x, c.x); r.y = fmaf(s, v.y, c.y); return r;
}
DEV_INLINE v2f pk_mul(float s, v2f v) {
  v2f r; r.x = s * v.x; r.y = s * v.y; return r;
}
DEV_INLINE v2f swapneg(v2f w) {   // (wr,wi) -> (-wi, wr)  [i * w]
  v2f r; r.x = -w.y; r.y = w.x; return r;
}

#if __has_builtin(__builtin_amdgcn_exp2f)
#define EXP2F(x) __builtin_amdgcn_exp2f(x)
#else
#define EXP2F(x) exp2f(x)
#endif
#if __has_builtin(__builtin_amdgcn_sinf)
#define SINR(x) __builtin_amdgcn_sinf(x)   // sin(2*pi*x), x in revolutions
#define COSR(x) __builtin_amdgcn_cosf(x)
#else
#define SINR(x) __sinf((x) * 6.2831853f)
#define COSR(x) __cosf((x) * 6.2831853f)
#endif

#if __has_builtin(__builtin_amdgcn_global_load_lds)
#define HAVE_GLDS 1
#define GLOAD16(g, l)                                                         \
  __builtin_amdgcn_global_load_lds(                                           \
      (const __attribute__((address_space(1))) unsigned int*)(g),             \
      (__attribute__((address_space(3))) unsigned int*)(l), 16, 0, 0)
#else
#define HAVE_GLDS 0
#endif

// Taylor sin/cos order 7/6 (radians), |th| <= ~1, err < 3e-5. Shares t2.
DEV_INLINE void sincos_poly(float th, float& s, float& c) {
  float t2 = th * th;
  float u = fmaf(t2, -1.9841270e-4f, 8.3333333e-3f);
  u = fmaf(t2, u, -0.16666667f);
  u = fmaf(t2, u, 1.f);
  s = th * u;
  float v = fmaf(t2, -1.3888889e-3f, 4.1666667e-2f);
  v = fmaf(t2, v, -0.5f);
  c = fmaf(t2, v, 1.f);
}

// DPP 16-lane add-reduce (quad_perm xor1, xor2, row_ror:4, row_ror:8)
template <int CTRL>
DEV_INLINE float dpp_add(float v) {
  int x = __builtin_amdgcn_update_dpp(0, __float_as_int(v), CTRL, 0xF, 0xF, true);
  return v + __int_as_float(x);
}

// ---------------------------------------------------------------------------
// f32 -> bf16 convert, 3 segments + padded x_proj_w (97->128 rows) as seg 4.
// ---------------------------------------------------------------------------
__global__ __launch_bounds__(256) void cvt4_k(
    const float* __restrict__ i0, unsigned short* __restrict__ o0, int n0,
    const float* __restrict__ i1, unsigned short* __restrict__ o1, int n1,
    const float* __restrict__ i2, unsigned short* __restrict__ o2, int n2,
    const float* __restrict__ xw, unsigned short* __restrict__ xwpb) {
  int i = blockIdx.x * 256 + threadIdx.x;   // in float4 units
  if (i < n0) {
    float4 v = ((const float4*)i0)[i];
    ((ushort4*)o0)[i] = make_ushort4(f2bf(v.x), f2bf(v.y), f2bf(v.z), f2bf(v.w));
  } else if (i < n0 + n1) {
    int off = i - n0;
    float4 v = ((const float4*)i1)[off];
    ((ushort4*)o1)[off] = make_ushort4(f2bf(v.x), f2bf(v.y), f2bf(v.z), f2bf(v.w));
  } else if (i < n0 + n1 + n2) {
    int off = i - n0 - n1;
    float4 v = ((const float4*)i2)[off];
    ((ushort4*)o2)[off] = make_ushort4(f2bf(v.x), f2bf(v.y), f2bf(v.z), f2bf(v.w));
  } else {
    int off = i - n0 - n1 - n2;
    if (off < 128 * 256) {
      int row = off >> 8;
      float4 v = (row < PW) ? ((const float4*)xw)[off] : make_float4(0, 0, 0, 0);
      ((ushort4*)xwpb)[off] = make_ushort4(f2bf(v.x), f2bf(v.y), f2bf(v.z), f2bf(v.w));
    }
  }
}

// ---------------------------------------------------------------------------
// Shared GEMM helpers: global_load_lds staging with SOURCE-side XOR swizzle
// (linear LDS dest); reads use swz().
// ---------------------------------------------------------------------------
DEV_INLINE int swz(int row, int kb) { return (row << 7) + (kb ^ ((row & 7) << 4)); }

DEV_INLINE void stage16(const short* g, char* l) {
#if HAVE_GLDS
  GLOAD16(g, l);
#else
  *(bf16x8*)l = *(const bf16x8*)g;
#endif
}

#define GEMM_STAGE(Abase, Wbase)                                              \
  _Pragma("unroll")                                                           \
  for (int i = 0; i < 2; ++i) {                                               \
    int off = i * 4096 + tid * 16;                                            \
    int row = off >> 7, kb = off & 127;                                       \
    int kel = (kb ^ ((row & 7) << 4)) >> 1;                                   \
    stage16(Abase + (size_t)(bm + row) * K + k0 + kel, ldsb + off);           \
    stage16(Wbase + (size_t)(bn + row) * K + k0 + kel, ldsb + 8192 + off);    \
  }

#define GEMM_MFMA_BODY                                                        \
  _Pragma("unroll")                                                           \
  for (int ks = 0; ks < 2; ++ks) {                                            \
    const int kb = ks * 64 + ((lane >> 4) << 4);                              \
    bf16x8 af = *(const bf16x8*)(ldsb + swz(wv * 16 + (lane & 15), kb));      \
    _Pragma("unroll")                                                         \
    for (int nb = 0; nb < 4; ++nb) {                                          \
      bf16x8 bfv = *(const bf16x8*)(ldsb + 8192 + swz(nb * 16 + (lane & 15), kb)); \
      acc[nb] = __builtin_amdgcn_mfma_f32_16x16x32_bf16(af, bfv, acc[nb], 0, 0, 0); \
    }                                                                         \
  }

// ---------------------------------------------------------------------------
// gemm1: C = xb @ wb1^T (N=2048). z-half tiles (bn >= DI) write silu(v)
// directly to sz (uniform per block); x-half writes xz.
// ---------------------------------------------------------------------------
__global__ __launch_bounds__(256) void gemm1_k(
    const short* __restrict__ A, const short* __restrict__ W,
    float* __restrict__ C, float* __restrict__ szp, int M, int N, int K) {
  __shared__ char ldsb[16384];
  const int tid = threadIdx.x;
  const int lane = tid & 63, wv = tid >> 6;
  const int bm = blockIdx.y * 64, bn = blockIdx.x * 64;

  f32x4 acc[4];
#pragma unroll
  for (int nb = 0; nb < 4; ++nb) acc[nb] = (f32x4){0.f, 0.f, 0.f, 0.f};

  for (int k0 = 0; k0 < K; k0 += 64) {
    GEMM_STAGE(A, W)
    __syncthreads();
    GEMM_MFMA_BODY
    __syncthreads();
  }
  const bool zside = (bn >= DI);
#pragma unroll
  for (int nb = 0; nb < 4; ++nb) {
    int col = bn + nb * 16 + (lane & 15);
    int row0 = bm + wv * 16 + ((lane >> 4) << 2);
#pragma unroll
    for (int j = 0; j < 4; ++j) {
      float v = acc[nb][j];
      if (zside)
        szp[(size_t)(row0 + j) * DI + col - DI] = v * sigmoidf_(v);
      else
        C[(size_t)(row0 + j) * N + col] = v;
    }
  }
}

// 64x64-tile split-K GEMM (proj + gemm2): KS-wide K slice per blockIdx.z.
__global__ __launch_bounds__(256) void gemm_bf16_sk(
    const short* __restrict__ A, const short* __restrict__ W,
    float* __restrict__ P, int M, int N, int K, int KS) {
  __shared__ char ldsb[16384];
  const int tid = threadIdx.x;
  const int lane = tid & 63, wv = tid >> 6;
  const int bm = blockIdx.y * 64, bn = blockIdx.x * 64;
  const int kz = blockIdx.z * KS;
  float* Cp = P + (size_t)blockIdx.z * M * N;

  f32x4 acc[4];
#pragma unroll
  for (int nb = 0; nb < 4; ++nb) acc[nb] = (f32x4){0.f, 0.f, 0.f, 0.f};

  for (int k0 = kz; k0 < kz + KS; k0 += 64) {
    GEMM_STAGE(A, W)
    __syncthreads();
    GEMM_MFMA_BODY
    __syncthreads();
  }
#pragma unroll
  for (int nb = 0; nb < 4; ++nb) {
    int col = bn + nb * 16 + (lane & 15);
    int row0 = bm + wv * 16 + ((lane >> 4) << 2);
#pragma unroll
    for (int j = 0; j < 4; ++j)
      Cp[(size_t)(row0 + j) * N + col] = acc[nb][j];
  }
}

// out = sum of 4 K-slice partials (float4 vectorized)
__global__ __launch_bounds__(256) void addp4_k(
    const float4* __restrict__ p, float4* __restrict__ out) {
  constexpr int NN = ML * DM / 4;
  int i = blockIdx.x * 256 + threadIdx.x;
  float4 a = p[i], b = p[i + NN], c = p[i + 2 * NN], d = p[i + 3 * NN];
  out[i] = make_float4(a.x + b.x + c.x + d.x, a.y + b.y + c.y + d.y,
                       a.z + b.z + c.z + d.z, a.w + b.w + c.w + d.w);
}

// ---------------------------------------------------------------------------
// causal depthwise conv (K=3) + bias + SiLU -> xcb (bf16). Reads x-half only.
// ---------------------------------------------------------------------------
__global__ __launch_bounds__(256) void conv_silu_k(
    const float* __restrict__ xz, const float* __restrict__ cw,
    const float* __restrict__ cb, unsigned short* __restrict__ xcb) {
  int idx = blockIdx.x * 256 + threadIdx.x;   // float4 unit: (m, d4)
  int m = idx >> 8, d4 = (idx & 255) * 4;
  int t = m & (L - 1);
  const float* base = xz + (size_t)m * (2 * DI);
  float4 r2 = *(const float4*)(base + d4);
  float4 r1 = (t >= 1) ? *(const float4*)(base - 2 * DI + d4) : make_float4(0, 0, 0, 0);
  float4 r0 = (t >= 2) ? *(const float4*)(base - 4 * DI + d4) : make_float4(0, 0, 0, 0);
  float wv[12];
  *(float4*)(wv + 0) = *(const float4*)(cw + d4 * 3 + 0);
  *(float4*)(wv + 4) = *(const float4*)(cw + d4 * 3 + 4);
  *(float4*)(wv + 8) = *(const float4*)(cw + d4 * 3 + 8);
  float4 bv = *(const float4*)(cb + d4);
  float rin0[4] = {r0.x, r0.y, r0.z, r0.w};
  float rin1[4] = {r1.x, r1.y, r1.z, r1.w};
  float rin2[4] = {r2.x, r2.y, r2.z, r2.w};
  float bb[4] = {bv.x, bv.y, bv.z, bv.w};
  float xo[4];
#pragma unroll
  for (int j = 0; j < 4; ++j) {
    float v = bb[j];
    v = fmaf(rin0[j], wv[3 * j + 0], v);
    v = fmaf(rin1[j], wv[3 * j + 1], v);
    v = fmaf(rin2[j], wv[3 * j + 2], v);
    xo[j] = v * sigmoidf_(v);
  }
  ((ushort4*)xcb)[idx] = make_ushort4(f2bf(xo[0]), f2bf(xo[1]), f2bf(xo[2]), f2bf(xo[3]));
}

// ---------------------------------------------------------------------------
// FUSED: reduce 8 proj partials -> scatter B/C (interleaved bcc4) + lam,
// keep dt columns in LDS, compute delta = softplus(dt@dt_w^T+dt_b) -> dx2.
// ---------------------------------------------------------------------------
__global__ __launch_bounds__(256) void reduce_delta_k(
    const float* __restrict__ P, const float* __restrict__ dtw,
    const float* __restrict__ dtb, const unsigned short* __restrict__ xcb,
    float* __restrict__ bcc4, float* __restrict__ lamv,
    float2* __restrict__ dx2) {
  __shared__ float pp[2][32];
  const int tid = threadIdx.x;
  const int i = blockIdx.x * 256 + tid;
  const int m = i >> 7, c = i & 127;
  float s = 0.f;
#pragma unroll
  for (int z = 0; z < 8; ++z) s += P[(size_t)z * ML * 128 + i];
  if (c < 32)       pp[tid >> 7][c] = s;
  else if (c < 48)  bcc4[(m * 16 + c - 32) * 4 + 0] = s;
  else if (c < 64)  bcc4[(m * 16 + c - 48) * 4 + 1] = s;
  else if (c < 80)  bcc4[(m * 16 + c - 64) * 4 + 2] = s;
  else if (c < 96)  bcc4[(m * 16 + c - 80) * 4 + 3] = s;
  else if (c == 96) lamv[m] = sigmoidf_(s);
  __syncthreads();
  const int d0 = tid * 4;
  const int m0 = blockIdx.x * 2;
  float4 bb4 = *(const float4*)(dtb + d0);
  float acc[2][4];
#pragma unroll
  for (int r = 0; r < 2; ++r) {
    acc[r][0] = bb4.x; acc[r][1] = bb4.y; acc[r][2] = bb4.z; acc[r][3] = bb4.w;
  }
#pragma unroll
  for (int j = 0; j < 4; ++j) {
    const float4* wrow = (const float4*)(dtw + (size_t)(d0 + j) * 32);
#pragma unroll
    for (int kq = 0; kq < 8; ++kq) {
      float4 w4 = wrow[kq];
#pragma unroll
      for (int r = 0; r < 2; ++r) {
        acc[r][j] = fmaf(pp[r][kq * 4 + 0], w4.x, acc[r][j]);
        acc[r][j] = fmaf(pp[r][kq * 4 + 1], w4.y, acc[r][j]);
        acc[r][j] = fmaf(pp[r][kq * 4 + 2], w4.z, acc[r][j]);
        acc[r][j] = fmaf(pp[r][kq * 4 + 3], w4.w, acc[r][j]);
      }
    }
  }
#pragma unroll
  for (int r = 0; r < 2; ++r) {
    ushort4 xv = ((const ushort4*)xcb)[((size_t)(m0 + r) * DI + d0) >> 2];
    float dl[4];
#pragma unroll
    for (int j = 0; j < 4; ++j) {
      float xq = acc[r][j];
      dl[j] = (xq > 20.f) ? xq : log1pf(__expf(xq));
    }
    *(float4*)(dx2 + (size_t)(m0 + r) * DI + d0) =
        make_float4(dl[0], bf2f(xv.x), dl[1], bf2f(xv.y));
    *(float4*)(dx2 + (size_t)(m0 + r) * DI + d0 + 2) =
        make_float4(dl[2], bf2f(xv.z), dl[3], bf2f(xv.w));
  }
}

// ---------------------------------------------------------------------------
// LDS-staged chunked scan with packed-f32 complex math.
// h' = ar*w + ai*(i*w) + g*Bx, w = h + bsc*Bxp  (all v2f, v_pk_fma targets)
// ---------------------------------------------------------------------------
template <bool PASS_B>
__global__ __launch_bounds__(256, 8) void scan_pass(
    const float2* __restrict__ dx2, const float* __restrict__ lamv,
    const float4* __restrict__ bcc4, const float* __restrict__ sz,
    const float* __restrict__ A_log, const float* __restrict__ A_imag,
    const float* __restrict__ D_skip,
    float2* __restrict__ aggA, float2* __restrict__ aggU,
    unsigned short* __restrict__ ybuf) {
  __shared__ float4 qx[CL][17];                  // {dlt, xt, bsc, g} (padded)
  __shared__ float2 bcl[PASS_B ? 1 : CL][17];    // pass A: {Br, Bi}
  __shared__ float4 bccl[PASS_B ? CL : 1][17];   // pass B: {Br,Bi,Cr,Ci}
  __shared__ float  ylds[PASS_B ? CL : 1][17];   // y per (t, ch)

  const int tid = threadIdx.x;
  const int n = tid & 15, ch = tid >> 4;
  const int bx = blockIdx.x, c = blockIdx.y;
  const int b = bx >> 6, d0 = (bx & 63) * 16;
  const int d = d0 + ch;
  const int lane = bx * 256 + tid;
  const int t0 = c * CL, mb = b * L;

  // ---- stage chunk into LDS ----
  {
    int t = tid >> 3, pr = tid & 7;              // 32 t x 8 pairs
    size_t row = (size_t)(mb + t0 + t);
    float4 v = *(const float4*)(dx2 + row * DI + d0 + pr * 2);
    float lamt = lamv[row];
    float g0 = lamt * v.x, g1 = lamt * v.z;
    qx[t][pr * 2 + 0] = make_float4(v.x, v.y, v.x - g0, g0);
    qx[t][pr * 2 + 1] = make_float4(v.z, v.w, v.z - g1, g1);
    float4 b0 = bcc4[row * 16 + pr * 2 + 0];
    float4 b1 = bcc4[row * 16 + pr * 2 + 1];
    if constexpr (PASS_B) {
      bccl[t][pr * 2 + 0] = b0;
      bccl[t][pr * 2 + 1] = b1;
    } else {
      bcl[t][pr * 2 + 0] = make_float2(b0.x, b0.y);
      bcl[t][pr * 2 + 1] = make_float2(b1.x, b1.y);
    }
  }

  const float Ar = -__expf(A_log[d * 16 + n]);
  const float Arl = Ar * 1.44269504f;                  // * log2(e)
  const float Ai = A_imag[d * 16 + n];

  v2f Bxp = (v2f){0.f, 0.f};
  if (c > 0) {
    float xp = dx2[(size_t)(mb + t0 - 1) * DI + d].y;
    float4 bp = bcc4[(size_t)(mb + t0 - 1) * 16 + n];
    Bxp.x = bp.x * xp; Bxp.y = bp.y * xp;
  }
  v2f h = (v2f){0.f, 0.f};
  float S = 0.f, Dsk = 0.f;
  if (PASS_B) {
    if (c > 0) {
      float2 h0 = aggU[(c - 1) * NLANES + lane];  // prefix from combine
      h.x = h0.x; h.y = h0.y;
    }
    Dsk = D_skip[d];
  }

  __syncthreads();

  // ---- recurrence: pure LDS + packed VALU ----
#pragma unroll
  for (int t = 0; t < CL; ++t) {
    float4 q = qx[t][ch];
    v2f Bv; float Cr_ = 0.f, Ci_ = 0.f;
    if constexpr (PASS_B) {
      float4 p = bccl[t][n];
      Bv.x = p.x; Bv.y = p.y; Cr_ = p.z; Ci_ = p.w;
    } else {
      float2 p = bcl[t][n];
      Bv.x = p.x; Bv.y = p.y;
    }
    float ear = EXP2F(q.x * Arl);
    float sn, cs; sincos_poly(q.x * Ai, sn, cs);
    float ar = ear * cs, ai = ear * sn;
    v2f Bx = pk_mul(q.y, Bv);
    v2f w = pk_fma(q.z, Bxp, h);
    v2f tg = pk_mul(q.w, Bx);
    h = pk_fma(ar, w, pk_fma(ai, swapneg(w), tg));
    Bxp = Bx;
    if constexpr (!PASS_B) {
      S += q.x;
    } else {
      float yc = fmaf(h.y, Ci_, h.x * Cr_);   // Re(h * conj(C))
      yc = dpp_add<0xB1>(yc);
      yc = dpp_add<0x4E>(yc);
      yc = dpp_add<0x124>(yc);
      yc = dpp_add<0x128>(yc);
      if (n == 0) ylds[t][ch] = fmaf(Dsk, q.y, yc);
    }
  }

  if constexpr (!PASS_B) {
    float earS = EXP2F(S * Arl);
    float rvS = S * Ai * 0.15915494f;     // revolutions for HW sin/cos
    float AaR = earS * COSR(rvS);
    float AaI = earS * SINR(rvS);
    int idx = c * NLANES + lane;
    aggA[idx] = make_float2(AaR, AaI);
    aggU[idx] = make_float2(h.x, h.y);
  } else {
    __syncthreads();
    // coalesced epilogue: y * silu(z) -> packed bf16 pairs
    int t = tid >> 3, pr = tid & 7;
    size_t row = (size_t)(mb + t0 + t);
    float2 szv = *(const float2*)(sz + row * DI + d0 + pr * 2);
    float y0 = ylds[t][pr * 2 + 0] * szv.x;
    float y1 = ylds[t][pr * 2 + 1] * szv.y;
    unsigned pk = (unsigned)f2bf(y0) | ((unsigned)f2bf(y1) << 16);
    *(unsigned*)(ybuf + row * DI + d0 + pr * 2) = pk;
  }
}

// in-place prefix: after this, aggU[c] = chunk-(c+1) entry state (packed)
__global__ __launch_bounds__(256) void scan_combine_k(
    const float2* __restrict__ aggA, float2* __restrict__ aggU) {
  int gid = blockIdx.x * 256 + threadIdx.x;
  v2f h = (v2f){0.f, 0.f};
#pragma unroll
  for (int c = 0; c < NCHUNK - 1; ++c) {
    float2 a = aggA[c * NLANES + gid];
    float2 u = aggU[c * NLANES + gid];
    v2f uv; uv.x = u.x; uv.y = u.y;
    h = pk_fma(a.x, h, pk_fma(a.y, swapneg(h), uv));
    aggU[c * NLANES + gid] = make_float2(h.x, h.y);
  }
}

extern "C" void kernel_launch(void* const* d_in, const int* in_sizes, int n_in,
                              void* d_out, int out_size, void* d_ws, size_t ws_size,
                              hipStream_t stream) {
  const float* x        = (const float*)d_in[0];
  const float* in_proj  = (const float*)d_in[1];
  const float* conv_w   = (const float*)d_in[2];
  const float* conv_b   = (const float*)d_in[3];
  const float* x_proj_w = (const float*)d_in[4];
  const float* dt_w     = (const float*)d_in[5];
  const float* dt_b     = (const float*)d_in[6];
  const float* A_log    = (const float*)d_in[7];
  const float* A_imag   = (const float*)d_in[8];
  const float* D_skip   = (const float*)d_in[9];
  const float* out_proj = (const float*)d_in[10];
  float* out = (float*)d_out;

  float* ws = (float*)d_ws;
  float*  xz    = ws; ws += (size_t)ML * 2 * DI;   // gemm1 out; later partials
  float*  sz    = ws; ws += (size_t)ML * DI;
  float2* dx2   = (float2*)ws; ws += (size_t)ML * DI * 2;
  float*  bcc4  = ws; ws += (size_t)ML * 64;       // float4[ML*16]
  float*  lamv  = ws; ws += ML;
  float2* aggA  = (float2*)ws; ws += (size_t)NCHUNK * NLANES * 2;
  float2* aggU  = (float2*)ws; ws += (size_t)NCHUNK * NLANES * 2;
  unsigned short* xb   = (unsigned short*)ws; ws += (size_t)ML * DM / 2;
  unsigned short* wb1  = (unsigned short*)ws; ws += (size_t)(2 * DI) * DM / 2;
  unsigned short* wb2  = (unsigned short*)ws; ws += (size_t)DM * DI / 2;
  unsigned short* xcb  = (unsigned short*)ws; ws += (size_t)ML * DI / 2;
  unsigned short* xwpb = (unsigned short*)ws; ws += (size_t)128 * DI / 2;
  unsigned short* ybuf = (unsigned short*)ws; ws += (size_t)ML * DI / 2;

  const int n0 = ML * DM / 4, n1 = 2 * DI * DM / 4, n2 = DM * DI / 4;
  const int n3 = 128 * DI / 4;
  cvt4_k<<<(n0 + n1 + n2 + n3 + 255) / 256, 256, 0, stream>>>(
      x, xb, n0, in_proj, wb1, n1, out_proj, wb2, n2, x_proj_w, xwpb);
  gemm1_k<<<dim3(2 * DI / 64, ML / 64), 256, 0, stream>>>(
      (const short*)xb, (const short*)wb1, xz, sz, ML, 2 * DI, DM);
  conv_silu_k<<<ML * DI / 4 / 256, 256, 0, stream>>>(xz, conv_w, conv_b, xcb);
  gemm_bf16_sk<<<dim3(2, ML / 64, 8), 256, 0, stream>>>(
      (const short*)xcb, (const short*)xwpb, xz, ML, 128, DI, 128);
  reduce_delta_k<<<ML * 128 / 256, 256, 0, stream>>>(xz, dt_w, dt_b, xcb,
                                                     bcc4, lamv, dx2);
  scan_pass<false><<<dim3(128, NCHUNK - 1), 256, 0, stream>>>(
      dx2, lamv, (const float4*)bcc4, sz, A_log, A_imag, D_skip,
      aggA, aggU, nullptr);
  scan_combine_k<<<NLANES / 256, 256, 0, stream>>>(aggA, aggU);
  scan_pass<true><<<dim3(128, NCHUNK), 256, 0, stream>>>(
      dx2, lamv, (const float4*)bcc4, sz, A_log, A_imag, D_skip,
      aggA, aggU, ybuf);
  gemm_bf16_sk<<<dim3(DM / 64, ML / 64, 4), 256, 0, stream>>>(
      (const short*)ybuf, (const short*)wb2, xz, ML, DM, DI, 256);
  addp4_k<<<ML * DM / 4 / 256, 256, 0, stream>>>((const float4*)xz, (float4*)out);
}